// Round 8
// baseline (2512.641 us; speedup 1.0000x reference)
//
#include <hip/hip_runtime.h>

typedef short bf16x8 __attribute__((ext_vector_type(8)));
typedef float f32x4 __attribute__((ext_vector_type(4)));
typedef float f32x2 __attribute__((ext_vector_type(2)));
typedef unsigned short u16;
typedef unsigned int u32;
typedef unsigned long long u64;

#define NPTS 16384
#define NPOINT 1024
#define STOT 524288   // 16*1024*32 samples
#define NCB 240       // conv blocks (blocks 16..255)
#define NW  960       // conv workers (4-wave groups)

__device__ __forceinline__ u16 f2bf(float f){
  u32 u = __builtin_bit_cast(u32, f);
  u += 0x7fffu + ((u >> 16) & 1u);
  return (u16)(u >> 16);
}
__device__ __forceinline__ float bf2f(u16 u){
  u32 x = ((u32)u) << 16;
  return __builtin_bit_cast(float, x);
}

// f32 max-combine across lanes via DPP (1-2 VALU insts per level).
template<int CTRL>
__device__ __forceinline__ float dpp_maxf(float v){
  int x = __builtin_amdgcn_update_dpp(0, __builtin_bit_cast(int, v), CTRL, 0xf, 0xf, true);
  return fmaxf(v, __builtin_bit_cast(float, x));
}
// 64-bit max-combine across lanes via DPP (exact-tie fallback path).
template<int CTRL>
__device__ __forceinline__ u64 dpp_max(u64 key){
  u32 lo = (u32)key, hi = (u32)(key >> 32);
  u32 lo1 = (u32)__builtin_amdgcn_update_dpp(0, (int)lo, CTRL, 0xf, 0xf, true);
  u32 hi1 = (u32)__builtin_amdgcn_update_dpp(0, (int)hi, CTRL, 0xf, 0xf, true);
  u64 k1 = ((u64)hi1 << 32) | (u64)lo1;
  return (k1 > key) ? k1 : key;
}
__device__ __forceinline__ u64 packkey(float d, int idx){
  // d >= 0 so uint order on float bits == float order; ~idx -> ties pick smaller idx
  return ((u64)__builtin_bit_cast(u32, d) << 32) | (u64)(u32)(~(u32)idx);
}

__device__ __forceinline__ void arrive(u32* c){
  __hip_atomic_fetch_add(c, 1u, __ATOMIC_RELEASE, __HIP_MEMORY_SCOPE_AGENT);
}
__device__ __forceinline__ void waitc(u32* c, u32 tgt){
  while (__hip_atomic_load(c, __ATOMIC_ACQUIRE, __HIP_MEMORY_SCOPE_AGENT) < tgt)
    __builtin_amdgcn_s_sleep(16);
}

struct FpsS  { uint2 wkey[2][16]; };
struct ConvS { float lsum[128]; float lsqr[128]; float av[128]; float dv[128]; };
union SMemU  { FpsS fps; ConvS conv; };

__device__ __forceinline__ bf16x8 load_bn_relu(const u16* __restrict__ row, int ko,
                                               const float* __restrict__ av,
                                               const float* __restrict__ dv){
  uint4 r = *(const uint4*)(row + ko);
  u32 w[4] = {r.x, r.y, r.z, r.w};
  bf16x8 out;
#pragma unroll
  for (int jj = 0; jj < 8; jj++){
    u16 us = (u16)(w[jj >> 1] >> ((jj & 1) * 16));
    float h = fmaxf(fmaf(av[ko + jj], bf2f(us), dv[ko + jj]), 0.f);
    out[jj] = (short)f2bf(h);
  }
  return out;
}

// zero the sync counters (ws is re-poisoned 0xAA before every call)
__global__ void zero_kernel(u32* __restrict__ ctrs){
  if (threadIdx.x < 64) ctrs[threadIdx.x] = 0;
}

// ================================================================ MEGA KERNEL
// blocks 0..15  : FPS — ONE barrier per iter: stage1 f32-DPP wave max +
//                 ballot index recovery (u64 fallback on exact ties) ->
//                 lane0 writes (idx,val) to ping-pong LDS -> barrier ->
//                 stage2 gives nb to ALL lanes -> uniform s_load center from
//                 global xpk (L2-hot). No owner-select, no second barrier.
// blocks 16..255: persistent conv chain (phases via device-scope counters).
// waves_per_eu(4,4): occupancy pinned at 16 waves/CU -> allocator free to use
// the full 128-reg/wave budget as arch VGPRs (minimize AGPR-move tax).
__global__ __attribute__((amdgpu_flat_work_group_size(1024,1024), amdgpu_waves_per_eu(4,4)))
void mega_kernel(
    const float* __restrict__ xyz, const float* __restrict__ points,
    const int* __restrict__ finit, const int* __restrict__ gidx,
    const float* __restrict__ W0, const float* __restrict__ g0v, const float* __restrict__ be0,
    const float* __restrict__ W1, const float* __restrict__ g1v, const float* __restrict__ be1,
    const float* __restrict__ W2, const float* __restrict__ g2v, const float* __restrict__ be2,
    float* __restrict__ out0, float* __restrict__ out1,
    u16* __restrict__ XP, u16* __restrict__ y0, u16* __restrict__ y1,
    float* __restrict__ maxb, float* __restrict__ minb,
    float* __restrict__ statsF, float4* __restrict__ xpk_all,
    u16* __restrict__ W0bf, u16* __restrict__ W1bf, u16* __restrict__ W2bf,
    u32* __restrict__ ctrs){
  __shared__ SMemU sm;
  const int t = threadIdx.x;
  const int wave = t >> 6, lane = t & 63;

  if (blockIdx.x < 16){
    // ------------------------------------------------------------ FPS path
    const int b = blockIdx.x;
    const float* xb = xyz + (size_t)b * 3 * NPTS;
    float4* xpk = xpk_all + (size_t)b * NPTS;
    f32x2 px[8], py[8], pz[8], dist[8];
#pragma unroll
    for (int j = 0; j < 8; j++){
      f32x2 x, y, z;
#pragma unroll
      for (int h = 0; h < 2; h++){
        int n = ((2*j + h) << 10) + t;
        x[h] = xb[n];
        y[h] = xb[NPTS + n];
        z[h] = xb[2*NPTS + n];
        xpk[n] = make_float4(x[h], y[h], z[h], 0.f);   // coalesced float4
      }
      px[j] = x; py[j] = y; pz[j] = z;
      f32x2 big = {1e10f, 1e10f};
      dist[j] = big;
    }
    int nbu = finit[b];
    __syncthreads();   // xpk writes drained (vmcnt0 per wave) -> L2 visible block-wide
    for (int it = 0; it < NPOINT; it++){
      const int p = it & 1;
      float4 cc = xpk[nbu];            // uniform index -> scalar load, L2-hot
      if (t == 0){
        out0[((size_t)b*3 + 0)*NPOINT + it] = cc.x;
        out0[((size_t)b*3 + 1)*NPOINT + it] = cc.y;
        out0[((size_t)b*3 + 2)*NPOINT + it] = cc.z;
      }
      float bv = -1.f; int bk = 0;
      {
#pragma clang fp contract(off)
        f32x2 cx2 = {cc.x, cc.x}, cy2 = {cc.y, cc.y}, cz2 = {cc.z, cc.z};
#pragma unroll
        for (int j = 0; j < 8; j++){
          f32x2 dx = px[j] - cx2;
          f32x2 dy = py[j] - cy2;
          f32x2 dz = pz[j] - cz2;
          f32x2 dd = dx*dx + dy*dy + dz*dz;   // matches reference eval order
          f32x2 dm = __builtin_elementwise_min(dist[j], dd);
          dist[j] = dm;
          bool g0 = dm.x > bv;
          bv = g0 ? dm.x : bv;  bk = g0 ? (2*j)   : bk;
          bool g1 = dm.y > bv;
          bv = g1 ? dm.y : bv;  bk = g1 ? (2*j+1) : bk;
        }
      }
      // ---- stage 1: wave max (f32 DPP) + index recovery via ballot
      float m = bv;
      m = dpp_maxf<0xB1>(m);   // xor1
      m = dpp_maxf<0x4E>(m);   // xor2
      m = dpp_maxf<0x141>(m);  // half_mirror (xor4)
      m = dpp_maxf<0x140>(m);  // mirror (xor8)
      m = dpp_maxf<0x142>(m);  // bcast15
      m = dpp_maxf<0x143>(m);  // bcast31 -> lane 63 holds wave max
      float ms = __builtin_bit_cast(float, __builtin_amdgcn_readlane(__builtin_bit_cast(int, m), 63));
      u64 mk = __ballot(bv == ms);
      u32 widx;
      if (__popcll(mk) == 1){
        int L = (int)__builtin_ctzll(mk);
        int kwin = __builtin_amdgcn_readlane(bk, L);
        widx = (u32)((kwin << 10) + (wave << 6) + L);
      } else {
        // exact-tie fallback: full u64 (dist,~idx) DPP chain
        u64 key = packkey(bv, (bk << 10) + t);
        key = dpp_max<0xB1>(key); key = dpp_max<0x4E>(key);
        key = dpp_max<0x141>(key); key = dpp_max<0x140>(key);
        key = dpp_max<0x142>(key); key = dpp_max<0x143>(key);
        u32 lo = (u32)__builtin_amdgcn_readlane((int)(u32)key, 63);
        widx = ~lo;
      }
      if (lane == 0){
        uint2 wk; wk.x = widx; wk.y = __builtin_bit_cast(u32, ms);
        sm.fps.wkey[p][wave] = wk;
      }
      __syncthreads();                 // the ONLY barrier per iter
      // ---- stage 2: reduce 16 wave keys; all lanes learn nb
      uint2 wk = sm.fps.wkey[p][lane & 15];
      float wv = __builtin_bit_cast(float, wk.y);
      float g4 = wv;
      g4 = dpp_maxf<0xB1>(g4); g4 = dpp_maxf<0x4E>(g4);
      g4 = dpp_maxf<0x141>(g4); g4 = dpp_maxf<0x140>(g4);
      float gms = __builtin_bit_cast(float, __builtin_amdgcn_readfirstlane(__builtin_bit_cast(int, g4)));
      u64 mk2 = __ballot(wv == gms);
      u32 lo16 = (u32)mk2 & 0xFFFFu;
      int nb;
      if (__popc(lo16) == 1){
        int w = (int)__builtin_ctz(lo16);
        nb = __builtin_amdgcn_readlane((int)wk.x, w);
      } else {
        u64 k2 = ((u64)wk.y << 32) | (u64)(u32)(~wk.x);
        k2 = dpp_max<0xB1>(k2); k2 = dpp_max<0x4E>(k2);
        k2 = dpp_max<0x141>(k2); k2 = dpp_max<0x140>(k2);
        u32 lo = (u32)__builtin_amdgcn_readfirstlane((int)(u32)k2);
        nb = (int)~lo;
      }
      nbu = __builtin_amdgcn_readfirstlane(nb);
    }
    return;
  }

  // -------------------------------------------------------------- conv path
  const int cb = blockIdx.x - 16;
  const int lw = wave & 3, g = wave >> 2;
  const int Wk = cb*4 + g;
  const int lrow = lane & 15, lq = lane >> 4;
  float* bsum0 = statsF;          float* bsqr0 = statsF + 8192;
  float* bsum1 = statsF + 16384;  float* bsqr1 = statsF + 24576;
  float* bsum2 = statsF + 32768;  float* bsqr2 = statsF + 40960;
  float* a0 = statsF + 49152;       float* d0 = a0 + 128;
  float* a1 = statsF + 49152 + 256; float* d1 = a1 + 128;
  float* a2 = statsF + 49152 + 512; float* d2 = a2 + 128;

  // ---- P0: pack XP + weight prep + zero stat buckets
  for (u32 idx = (u32)cb*1024u + t; idx < 16u*16384u; idx += (u32)NCB*1024u){
    u32 b = idx >> 14, n = idx & 16383u;
    const float* xb = xyz + (size_t)b*3*NPTS + n;
    const float* pb = points + (size_t)b*64*NPTS + n;
    u16* dst = XP + ((size_t)b*NPTS + n)*96;
#pragma unroll
    for (int half = 0; half < 2; half++){
      u32 w[24];
#pragma unroll
      for (int q = 0; q < 24; q++){
        int c0 = half*48 + 2*q, c1 = c0 + 1;
        float f0 = (c0 < 3) ? xb[(size_t)c0*NPTS] : (c0 < 67) ? pb[(size_t)(c0-3)*NPTS] : 0.f;
        float f1 = (c1 < 3) ? xb[(size_t)c1*NPTS] : (c1 < 67) ? pb[(size_t)(c1-3)*NPTS] : 0.f;
        w[q] = (u32)f2bf(f0) | ((u32)f2bf(f1) << 16);
      }
#pragma unroll
      for (int q = 0; q < 6; q++){
        uint4 v; v.x = w[4*q]; v.y = w[4*q+1]; v.z = w[4*q+2]; v.w = w[4*q+3];
        *(uint4*)(dst + half*48 + q*8) = v;
      }
    }
  }
  if (cb == 0){
    for (int i = t; i < 64*96; i += 1024){
      int nn = i / 96, kk = i % 96;
      W0bf[i] = (kk < 67) ? f2bf(W0[nn*67 + kk]) : (u16)0;
    }
    for (int i = t; i < 128*64; i += 1024) W1bf[i] = f2bf(W1[i]);
    for (int i = t; i < 128*128; i += 1024) W2bf[i] = f2bf(W2[i]);
  }
  if (cb == 1){
    for (int i = t; i < 49152; i += 1024) statsF[i] = 0.f;
  }
  __threadfence();
  __syncthreads();
  if (t == 0){ arrive(&ctrs[0]); waitc(&ctrs[0], NCB); }
  __syncthreads();

  // ---- P1: layer 0 (gather + K=96 matmul), stats accumulation
  if (t < 128){ sm.conv.lsum[t] = 0.f; sm.conv.lsqr[t] = 0.f; }
  __syncthreads();
  for (int j2 = Wk; j2 < 4096; j2 += NW){
    const int b = j2 >> 8;
    const size_t srow = (size_t)j2 * 128;
    const int gbase = b*32768 + (j2 & 255)*128;
    const int m0 = lw*32 + lrow, m1 = m0 + 16;
    const int p0 = gidx[gbase + m0];
    const int p1 = gidx[gbase + m1];
    const bf16x8* ar0 = (const bf16x8*)(XP + ((size_t)b*NPTS + p0)*96);
    const bf16x8* ar1 = (const bf16x8*)(XP + ((size_t)b*NPTS + p1)*96);
    f32x4 acc[2][4];
#pragma unroll
    for (int mt = 0; mt < 2; mt++)
#pragma unroll
      for (int nt = 0; nt < 4; nt++){ f32x4 z = {0.f,0.f,0.f,0.f}; acc[mt][nt] = z; }
#pragma unroll
    for (int ks = 0; ks < 3; ks++){
      bf16x8 af0 = ar0[ks*4 + lq];
      bf16x8 af1 = ar1[ks*4 + lq];
#pragma unroll
      for (int nt = 0; nt < 4; nt++){
        bf16x8 bb = *(const bf16x8*)(W0bf + (nt*16 + lrow)*96 + ks*32 + lq*8);
        acc[0][nt] = __builtin_amdgcn_mfma_f32_16x16x32_bf16(af0, bb, acc[0][nt], 0, 0, 0);
        acc[1][nt] = __builtin_amdgcn_mfma_f32_16x16x32_bf16(af1, bb, acc[1][nt], 0, 0, 0);
      }
    }
#pragma unroll
    for (int nt = 0; nt < 4; nt++){
      float s = 0.f, s2 = 0.f;
#pragma unroll
      for (int mt = 0; mt < 2; mt++){
#pragma unroll
        for (int i = 0; i < 4; i++){
          float u = acc[mt][nt][i];
          s += u; s2 = fmaf(u, u, s2);
          int m = lw*32 + mt*16 + lq*4 + i;
          y0[(srow + m)*64 + nt*16 + lrow] = f2bf(u);
        }
      }
      s  += __shfl_xor(s, 16, 64);  s  += __shfl_xor(s, 32, 64);
      s2 += __shfl_xor(s2, 16, 64); s2 += __shfl_xor(s2, 32, 64);
      if (lane < 16){ atomicAdd(&sm.conv.lsum[nt*16 + lane], s); atomicAdd(&sm.conv.lsqr[nt*16 + lane], s2); }
    }
  }
  __syncthreads();
  if (t < 64){
    atomicAdd(&bsum0[(cb & 63)*128 + t], sm.conv.lsum[t]);
    atomicAdd(&bsqr0[(cb & 63)*128 + t], sm.conv.lsqr[t]);
  }
  __threadfence();
  __syncthreads();
  if (t == 0) arrive(&ctrs[1]);
  if (cb == 0){
    if (t == 0) waitc(&ctrs[1], NCB);
    __syncthreads();
    if (t < 64){
      float s = 0.f, s2 = 0.f;
      for (int k = 0; k < 64; k++){ s += bsum0[k*128 + t]; s2 += bsqr0[k*128 + t]; }
      const float inv = 1.f / (float)STOT;
      float m = s * inv, v = s2 * inv - m*m;
      float aa = g0v[t] / sqrtf(v + 1e-5f);
      a0[t] = aa; d0[t] = be0[t] - m*aa;
    }
    __threadfence();
    __syncthreads();
    if (t == 0) arrive(&ctrs[2]);
  }
  if (t == 0) waitc(&ctrs[2], 1);
  __syncthreads();

  // ---- P2: layer 1 (K=64 -> 128)
  if (t < 128){ sm.conv.lsum[t] = 0.f; sm.conv.lsqr[t] = 0.f; }
  if (t < 64){ sm.conv.av[t] = a0[t]; sm.conv.dv[t] = d0[t]; }
  __syncthreads();
  for (int j2 = Wk; j2 < 4096; j2 += NW){
    const size_t srow = (size_t)j2 * 128;
    const int m0 = lw*32 + lrow, m1 = m0 + 16;
    const u16* row0 = y0 + (srow + m0)*64;
    const u16* row1 = y0 + (srow + m1)*64;
    f32x4 acc[2][8];
#pragma unroll
    for (int mt = 0; mt < 2; mt++)
#pragma unroll
      for (int nt = 0; nt < 8; nt++){ f32x4 z = {0.f,0.f,0.f,0.f}; acc[mt][nt] = z; }
#pragma unroll
    for (int ks = 0; ks < 2; ks++){
      const int ko = ks*32 + lq*8;
      bf16x8 af0 = load_bn_relu(row0, ko, sm.conv.av, sm.conv.dv);
      bf16x8 af1 = load_bn_relu(row1, ko, sm.conv.av, sm.conv.dv);
#pragma unroll
      for (int nt = 0; nt < 8; nt++){
        bf16x8 bb = *(const bf16x8*)(W1bf + (nt*16 + lrow)*64 + ko);
        acc[0][nt] = __builtin_amdgcn_mfma_f32_16x16x32_bf16(af0, bb, acc[0][nt], 0, 0, 0);
        acc[1][nt] = __builtin_amdgcn_mfma_f32_16x16x32_bf16(af1, bb, acc[1][nt], 0, 0, 0);
      }
    }
#pragma unroll
    for (int nt = 0; nt < 8; nt++){
      float s = 0.f, s2 = 0.f;
#pragma unroll
      for (int mt = 0; mt < 2; mt++){
#pragma unroll
        for (int i = 0; i < 4; i++){
          float u = acc[mt][nt][i];
          s += u; s2 = fmaf(u, u, s2);
          int m = lw*32 + mt*16 + lq*4 + i;
          y1[(srow + m)*128 + nt*16 + lrow] = f2bf(u);
        }
      }
      s  += __shfl_xor(s, 16, 64);  s  += __shfl_xor(s, 32, 64);
      s2 += __shfl_xor(s2, 16, 64); s2 += __shfl_xor(s2, 32, 64);
      if (lane < 16){ atomicAdd(&sm.conv.lsum[nt*16 + lane], s); atomicAdd(&sm.conv.lsqr[nt*16 + lane], s2); }
    }
  }
  __syncthreads();
  if (t < 128){
    atomicAdd(&bsum1[(cb & 63)*128 + t], sm.conv.lsum[t]);
    atomicAdd(&bsqr1[(cb & 63)*128 + t], sm.conv.lsqr[t]);
  }
  __threadfence();
  __syncthreads();
  if (t == 0) arrive(&ctrs[3]);
  if (cb == 0){
    if (t == 0) waitc(&ctrs[3], NCB);
    __syncthreads();
    if (t < 128){
      float s = 0.f, s2 = 0.f;
      for (int k = 0; k < 64; k++){ s += bsum1[k*128 + t]; s2 += bsqr1[k*128 + t]; }
      const float inv = 1.f / (float)STOT;
      float m = s * inv, v = s2 * inv - m*m;
      float aa = g1v[t] / sqrtf(v + 1e-5f);
      a1[t] = aa; d1[t] = be1[t] - m*aa;
    }
    __threadfence();
    __syncthreads();
    if (t == 0) arrive(&ctrs[4]);
  }
  if (t == 0) waitc(&ctrs[4], 1);
  __syncthreads();

  // ---- P3: layer 2 (K=128 -> 128) + per-group max/min of pre-BN y2
  if (t < 128){ sm.conv.lsum[t] = 0.f; sm.conv.lsqr[t] = 0.f;
                sm.conv.av[t] = a1[t]; sm.conv.dv[t] = d1[t]; }
  __syncthreads();
  for (int j2 = Wk; j2 < 4096; j2 += NW){
    const size_t srow = (size_t)j2 * 128;
    const int m0 = lw*32 + lrow, m1 = m0 + 16;
    const u16* row0 = y1 + (srow + m0)*128;
    const u16* row1 = y1 + (srow + m1)*128;
    f32x4 acc[2][8];
#pragma unroll
    for (int mt = 0; mt < 2; mt++)
#pragma unroll
      for (int nt = 0; nt < 8; nt++){ f32x4 z = {0.f,0.f,0.f,0.f}; acc[mt][nt] = z; }
#pragma unroll
    for (int ks = 0; ks < 4; ks++){
      const int ko = ks*32 + lq*8;
      bf16x8 af0 = load_bn_relu(row0, ko, sm.conv.av, sm.conv.dv);
      bf16x8 af1 = load_bn_relu(row1, ko, sm.conv.av, sm.conv.dv);
#pragma unroll
      for (int nt = 0; nt < 8; nt++){
        bf16x8 bb = *(const bf16x8*)(W2bf + (nt*16 + lrow)*128 + ko);
        acc[0][nt] = __builtin_amdgcn_mfma_f32_16x16x32_bf16(af0, bb, acc[0][nt], 0, 0, 0);
        acc[1][nt] = __builtin_amdgcn_mfma_f32_16x16x32_bf16(af1, bb, acc[1][nt], 0, 0, 0);
      }
    }
#pragma unroll
    for (int nt = 0; nt < 8; nt++){
      float s = 0.f, s2 = 0.f, mx = -3.4e38f, mn = 3.4e38f;
#pragma unroll
      for (int mt = 0; mt < 2; mt++){
#pragma unroll
        for (int i = 0; i < 4; i++){
          float u = acc[mt][nt][i];
          s += u; s2 = fmaf(u, u, s2);
          mx = fmaxf(mx, u); mn = fminf(mn, u);
        }
      }
      s  += __shfl_xor(s, 16, 64);  s  += __shfl_xor(s, 32, 64);
      s2 += __shfl_xor(s2, 16, 64); s2 += __shfl_xor(s2, 32, 64);
      mx = fmaxf(mx, __shfl_xor(mx, 16, 64)); mx = fmaxf(mx, __shfl_xor(mx, 32, 64));
      mn = fminf(mn, __shfl_xor(mn, 16, 64)); mn = fminf(mn, __shfl_xor(mn, 32, 64));
      if (lane < 16){
        size_t gi = ((size_t)j2*4 + lw)*128 + nt*16 + lane;
        maxb[gi] = mx; minb[gi] = mn;
        atomicAdd(&sm.conv.lsum[nt*16 + lane], s); atomicAdd(&sm.conv.lsqr[nt*16 + lane], s2);
      }
    }
  }
  __syncthreads();
  if (t < 128){
    atomicAdd(&bsum2[(cb & 63)*128 + t], sm.conv.lsum[t]);
    atomicAdd(&bsqr2[(cb & 63)*128 + t], sm.conv.lsqr[t]);
  }
  __threadfence();
  __syncthreads();
  if (t == 0) arrive(&ctrs[5]);
  if (cb == 0){
    if (t == 0) waitc(&ctrs[5], NCB);
    __syncthreads();
    if (t < 128){
      float s = 0.f, s2 = 0.f;
      for (int k = 0; k < 64; k++){ s += bsum2[k*128 + t]; s2 += bsqr2[k*128 + t]; }
      const float inv = 1.f / (float)STOT;
      float m = s * inv, v = s2 * inv - m*m;
      float aa = g2v[t] / sqrtf(v + 1e-5f);
      a2[t] = aa; d2[t] = be2[t] - m*aa;
    }
    __threadfence();
    __syncthreads();
    if (t == 0) arrive(&ctrs[6]);
  }
  if (t == 0) waitc(&ctrs[6], 1);
  __syncthreads();

  // ---- P4: final BN2+relu on group max/min, store [B,128,NP] (np coalesced)
  for (u32 e = (u32)cb*1024u + t; e < 16u*1024u*128u; e += (u32)NCB*1024u){
    u32 np = e & 1023u;
    u32 c  = (e >> 10) & 127u;
    u32 b  = e >> 17;
    size_t gi = ((size_t)b*1024 + np)*128 + c;
    float a = a2[c];
    float v = (a >= 0.f) ? maxb[gi] : minb[gi];
    out1[((size_t)b*128 + c)*1024 + np] = fmaxf(fmaf(a, v, d2[c]), 0.f);
  }
}

// ---------------------------------------------------------------- launch
extern "C" void kernel_launch(void* const* d_in, const int* in_sizes, int n_in,
                              void* d_out, int out_size, void* d_ws, size_t ws_size,
                              hipStream_t stream) {
  const float* xyz    = (const float*)d_in[0];
  const float* points = (const float*)d_in[1];
  const int*   finit  = (const int*)d_in[2];
  const int*   gidx   = (const int*)d_in[3];
  const float* W0  = (const float*)d_in[4];
  const float* g0v = (const float*)d_in[6];
  const float* be0 = (const float*)d_in[7];
  const float* W1  = (const float*)d_in[8];
  const float* g1v = (const float*)d_in[10];
  const float* be1 = (const float*)d_in[11];
  const float* W2  = (const float*)d_in[12];
  const float* g2v = (const float*)d_in[14];
  const float* be2 = (const float*)d_in[15];

  float* out0 = (float*)d_out;
  float* out1 = out0 + 16*3*NPOINT;   // 49152

  char* ws = (char*)d_ws;
  // layout (bytes):
  //   [0, 128M)            y1 (l1 out); XP aliases [0,48M) (dead before l1 writes)
  //   [128M, 192M)         y0 (l0 out); maxb/minb alias (y0 dead after l1)
  //   [192M, ...)          statsF, W*bf, xpk (4M, fps-only), ctrs
  u16* y1 = (u16*)ws;
  u16* XP = (u16*)ws;
  u16* y0 = (u16*)(ws + 134217728);
  float* maxb = (float*)(ws + 134217728);
  float* minb = (float*)(ws + 134217728 + 8388608);
  float* statsF = (float*)(ws + 201326592);
  u16* W0bf = (u16*)(ws + 201326592 + 49920*4);          // 201526272
  u16* W1bf = W0bf + 64*96;
  u16* W2bf = W1bf + 128*64;
  float4* xpk = (float4*)(ws + 201587712);               // 4 MiB
  u32* ctrs = (u32*)(ws + 205782016);                    // 64 u32

  zero_kernel<<<1, 64, 0, stream>>>(ctrs);
  mega_kernel<<<256, 1024, 0, stream>>>(
      xyz, points, finit, gidx,
      W0, g0v, be0, W1, g1v, be1, W2, g2v, be2,
      out0, out1, XP, y0, y1, maxb, minb, statsF, xpk,
      W0bf, W1bf, W2bf, ctrs);
}